// Round 3
// baseline (3846.930 us; speedup 1.0000x reference)
//
#include <hip/hip_runtime.h>
#include <stdint.h>

#define NB 64
#define NT 2048
#define NC 128
#define KF 32          // forward chunks per batch
#define LF 64          // forward chunk length
#define WF 16          // forward warmup steps

typedef _Float16 h2 __attribute__((ext_vector_type(2)));

__device__ __forceinline__ h2 bc2(uint32_t u) { return __builtin_bit_cast(h2, u); }

__device__ __forceinline__ float fdot2f(h2 a, h2 b, float c) {
#if __has_builtin(__builtin_amdgcn_fdot2)
  return __builtin_amdgcn_fdot2(a, b, c, false);
#else
  float d;
  asm("v_dot2_f32_f16 %0, %1, %2, %3"
      : "=v"(d)
      : "v"(__builtin_bit_cast(uint32_t, a)), "v"(__builtin_bit_cast(uint32_t, b)), "v"(c));
  return d;
#endif
}

#define DPP_FMAX_STAGE(vv, ctrl)                                               \
  {                                                                            \
    int t_ = __builtin_amdgcn_update_dpp(vv, vv, ctrl, 0xf, 0xf, false);       \
    vv = __builtin_bit_cast(int, fmaxf(__builtin_bit_cast(float, vv),          \
                                       __builtin_bit_cast(float, t_)));        \
  }

__device__ __forceinline__ float wave_max_bcast(float x) {
  int v = __builtin_bit_cast(int, x);
  DPP_FMAX_STAGE(v, 0x111);
  DPP_FMAX_STAGE(v, 0x112);
  DPP_FMAX_STAGE(v, 0x114);
  DPP_FMAX_STAGE(v, 0x118);
  DPP_FMAX_STAGE(v, 0x142);
  DPP_FMAX_STAGE(v, 0x143);
  return __builtin_bit_cast(float, __builtin_amdgcn_readlane(v, 63));
}

// Byte offset of one-hot row (b,t) inside d_out (floats: 64 nll + (b*T+t)*128).
// First 128 bytes of each 512B row slot temporarily hold uint8 backpointers.
__device__ __forceinline__ size_t slot_off(int b, int t) {
  return ((size_t)64 + ((size_t)b * NT + t) * NC) * 4;
}

union ScanSM {
  float tr[NC * NC];          // viterbi: fp32 transitions (64KB)
  uint32_t ea[4][2][64];      // forward: [wave][dbuf][lane] exp(alpha) fp16x2
};

// grid: blocks [0,64) = viterbi (wave 0 only); [64, 64+512) = forward, 4
// independent chunk-waves per block (no intra-block sync -> share 64KB alloc).
__global__ __launch_bounds__(256, 1) void scan_kernel(
    const float* __restrict__ em, const float* __restrict__ trans,
    const float* __restrict__ startv, const float* __restrict__ endv,
    float* __restrict__ out, float* __restrict__ fpart, int* __restrict__ best_last) {
  __shared__ __align__(16) ScanSM sm;
  const int lane = threadIdx.x & 63;
  const int wid = threadIdx.x >> 6;

  if (blockIdx.x >= NB) {
    // ================= forward chunks (log partition pieces) =================
    const int fi = (blockIdx.x - NB) * 4 + wid;   // chunk id 0..2047
    const int b = fi >> 5, c = fi & 31;
    const int t0 = (c == 0) ? 0 : c * LF - WF;
    const int tend = (c == KF - 1) ? (NT - 1) : (c + 1) * LF;
    const float* emb = em + (size_t)b * NT * NC;

    h2 e0[64], e1[64];
#pragma unroll
    for (int j = 0; j < 64; ++j) {
      float2 r0 = *(const float2*)(trans + (size_t)(2 * j) * NC + 2 * lane);
      float2 r1 = *(const float2*)(trans + (size_t)(2 * j + 1) * NC + 2 * lane);
      h2 a, bb;
      a.x = (_Float16)__expf(r0.x);  a.y = (_Float16)__expf(r1.x);
      bb.x = (_Float16)__expf(r0.y); bb.y = (_Float16)__expf(r1.y);
      e0[j] = a; e1[j] = bb;
    }
    float2 ev = *(const float2*)(endv + 2 * lane);
    float2 em0 = *(const float2*)(emb + (size_t)t0 * NC + 2 * lane);
    float2 nx0 = *(const float2*)(emb + (size_t)(t0 + 1) * NC + 2 * lane);
    float2 nx1 = *(const float2*)(emb + (size_t)(t0 + 2) * NC + 2 * lane);
    float2 nx2 = *(const float2*)(emb + (size_t)(t0 + 3) * NC + 2 * lane);
    float2 nx3 = *(const float2*)(emb + (size_t)(t0 + 4) * NC + 2 * lane);
    float u0 = em0.x, u1 = em0.y;
    if (c == 0) {
      float2 sv = *(const float2*)(startv + 2 * lane);
      u0 += sv.x; u1 += sv.y;
    }
    float mu = 0.f;
    uint32_t* eab0 = &sm.ea[wid][0][0];
    uint32_t* eab1 = &sm.ea[wid][1][0];

    auto fstep = [&](int t, float2& nx) {
      h2 eh; eh.x = (_Float16)__expf(u0); eh.y = (_Float16)__expf(u1);
      uint32_t* eab = (t & 1) ? eab1 : eab0;
      eab[lane] = __builtin_bit_cast(uint32_t, eh);
      float nm = wave_max_bcast(fmaxf(u0, u1));  // overlaps LDS round-trip
      asm volatile("s_waitcnt lgkmcnt(0)" ::: "memory");
      float A0 = 0.f, A1 = 0.f, A2 = 0.f, A3 = 0.f;
#pragma unroll
      for (int q = 0; q < 16; ++q) {
        uint4 w = *(const uint4*)&eab[q * 4];
        A0 = fdot2f(bc2(w.x), e0[4 * q + 0], A0); A1 = fdot2f(bc2(w.x), e1[4 * q + 0], A1);
        A2 = fdot2f(bc2(w.y), e0[4 * q + 1], A2); A3 = fdot2f(bc2(w.y), e1[4 * q + 1], A3);
        A0 = fdot2f(bc2(w.z), e0[4 * q + 2], A0); A1 = fdot2f(bc2(w.z), e1[4 * q + 2], A1);
        A2 = fdot2f(bc2(w.w), e0[4 * q + 3], A2); A3 = fdot2f(bc2(w.w), e1[4 * q + 3], A3);
      }
      float o0 = nx.x - nm, o1 = nx.y - nm;
      u0 = __logf(A0 + A2) + o0;
      u1 = __logf(A1 + A3) + o1;
      mu += nm;
      if (t + 4 <= tend) nx = *(const float2*)(emb + (size_t)(t + 4) * NC + 2 * lane);
    };

    auto wave_lse = [&](float x0, float x1) -> float {
      float m = wave_max_bcast(fmaxf(x0, x1));
      float ss = __expf(x0 - m) + __expf(x1 - m);
#pragma unroll
      for (int s = 1; s < 64; s <<= 1) ss += __shfl_xor(ss, s, 64);
      return m + __logf(ss);
    };

    int t = t0 + 1;
    float m_start = 0.f;
    if (c > 0) {
      for (int j = 0; j < WF / 4; ++j) {
        fstep(t, nx0); fstep(t + 1, nx1); fstep(t + 2, nx2); fstep(t + 3, nx3);
        t += 4;
      }
      m_start = mu + wave_lse(u0, u1);
    }
    for (; t + 3 <= tend; t += 4) {
      fstep(t, nx0); fstep(t + 1, nx1); fstep(t + 2, nx2); fstep(t + 3, nx3);
    }
    int rem = tend - t + 1;  // 0..3
    if (rem > 0) fstep(t, nx0);
    if (rem > 1) fstep(t + 1, nx1);
    if (rem > 2) fstep(t + 2, nx2);

    float m_end;
    if (c == KF - 1) m_end = mu + wave_lse(u0 + ev.x, u1 + ev.y);
    else             m_end = mu + wave_lse(u0, u1);
    if (lane == 0) fpart[b * KF + c] = m_end - m_start;
  } else {
    // ================= viterbi (exact fp32, pruned max-plus) ==================
    if (wid != 0) return;
    __builtin_amdgcn_s_setprio(1);
    const int b = blockIdx.x;
    const float* emb = em + (size_t)b * NT * NC;
    char* ob = (char*)out;
    float* smv = sm.tr;
#pragma unroll 8
    for (int r = 0; r < NC; ++r) {
      *(float2*)&smv[r * NC + 2 * lane] =
          *(const float2*)(trans + (size_t)r * NC + 2 * lane);
    }
    // per-row max/min for exact pruning (staggered -> conflict-free-ish)
    float rmx0 = -INFINITY, rmn0 = INFINITY, rmx1 = -INFINITY, rmn1 = INFINITY;
    {
      const float* r0 = &smv[(2 * lane) * NC];
      const float* r1 = &smv[(2 * lane + 1) * NC];
      for (int j = 0; j < 32; ++j) {
        int k = ((lane + j) & 31) * 4;
        float4 a = *(const float4*)(r0 + k);
        float4 bq = *(const float4*)(r1 + k);
        rmx0 = fmaxf(rmx0, fmaxf(fmaxf(a.x, a.y), fmaxf(a.z, a.w)));
        rmn0 = fminf(rmn0, fminf(fminf(a.x, a.y), fminf(a.z, a.w)));
        rmx1 = fmaxf(rmx1, fmaxf(fmaxf(bq.x, bq.y), fmaxf(bq.z, bq.w)));
        rmn1 = fminf(rmn1, fminf(fminf(bq.x, bq.y), fminf(bq.z, bq.w)));
      }
    }

    float2 sv = *(const float2*)(startv + 2 * lane);
    float2 ev = *(const float2*)(endv + 2 * lane);
    float2 em0 = *(const float2*)(emb + 2 * lane);
    float2 nx0 = *(const float2*)(emb + (size_t)1 * NC + 2 * lane);
    float2 nx1 = *(const float2*)(emb + (size_t)2 * NC + 2 * lane);
    float2 nx2 = *(const float2*)(emb + (size_t)3 * NC + 2 * lane);
    float2 nx3 = *(const float2*)(emb + (size_t)4 * NC + 2 * lane);
    float v0 = sv.x + em0.x, v1 = sv.y + em0.y;  // v[2*lane], v[2*lane+1]

    auto vstep = [&](int t, float2& nx) {
      // thr = max_cf fl(v[cf]+rowmin[cf]) <= winner(ct) for every ct (monotone fp)
      float thr = wave_max_bcast(fmaxf(v0 + rmn0, v1 + rmn1));
      unsigned long long remE = __ballot(v0 + rmx0 >= thr);  // even cf = 2*lane
      unsigned long long remO = __ballot(v1 + rmx1 >= thr);  // odd  cf = 2*lane+1
      float best0 = -INFINITY, best1 = -INFINITY;
      int bi0 = 0, bi1 = 0;

      auto nxt = [&](int fb) -> int {  // next candidate in ascending global cf
        int ce = remE ? 2 * (int)__builtin_ctzll(remE) : 1000;
        int co = remO ? 2 * (int)__builtin_ctzll(remO) + 1 : 1000;
        if (ce < co) { remE &= remE - 1; return ce; }
        if (co < 1000) { remO &= remO - 1; return co; }
        return fb;  // duplicate pad (idempotent under strict '>')
      };
      auto LD = [&](int cf) -> float2 { return *(const float2*)&smv[cf * NC + 2 * lane]; };
      auto PROC = [&](int cf, float2 T) {
        int half = cf >> 1;
        float vv = (cf & 1)
            ? __builtin_bit_cast(float, __builtin_amdgcn_readlane(__builtin_bit_cast(int, v1), half))
            : __builtin_bit_cast(float, __builtin_amdgcn_readlane(__builtin_bit_cast(int, v0), half));
        float s0 = vv + T.x, s1 = vv + T.y;
        bool g0 = s0 > best0; best0 = g0 ? s0 : best0; bi0 = g0 ? cf : bi0;
        bool g1 = s1 > best1; best1 = g1 ? s1 : best1; bi1 = g1 ? cf : bi1;
      };

      int A0 = nxt(0), A1 = nxt(A0), A2 = nxt(A0), A3 = nxt(A0);
      float2 TA0 = LD(A0), TA1 = LD(A1), TA2 = LD(A2), TA3 = LD(A3);
      bool hasB = (remE | remO) != 0ull;
      int B0 = 0, B1 = 0, B2 = 0, B3 = 0;
      float2 TB0 = {}, TB1 = {}, TB2 = {}, TB3 = {};
      if (hasB) {
        B0 = nxt(0); B1 = nxt(B0); B2 = nxt(B0); B3 = nxt(B0);
        TB0 = LD(B0); TB1 = LD(B1); TB2 = LD(B2); TB3 = LD(B3);
      }
      for (;;) {
        PROC(A0, TA0); PROC(A1, TA1); PROC(A2, TA2); PROC(A3, TA3);
        if (!hasB) break;
        A0 = B0; A1 = B1; A2 = B2; A3 = B3;
        TA0 = TB0; TA1 = TB1; TA2 = TB2; TA3 = TB3;
        hasB = (remE | remO) != 0ull;
        if (hasB) {
          B0 = nxt(0); B1 = nxt(B0); B2 = nxt(B0); B3 = nxt(B0);
          TB0 = LD(B0); TB1 = LD(B1); TB2 = LD(B2); TB3 = LD(B3);
        }
      }

      v0 = best0 + nx.x; v1 = best1 + nx.y;
      if (t + 4 < NT) nx = *(const float2*)(emb + (size_t)(t + 4) * NC + 2 * lane);
      uint16_t pkd = (uint16_t)((bi0 & 0xff) | (bi1 << 8));
      *(uint16_t*)(ob + slot_off(b, t) + 2 * lane) = pkd;  // bp bytes into d_out slot
    };
    int t = 1;
    for (; t + 3 < NT; t += 4) { vstep(t, nx0); vstep(t + 1, nx1); vstep(t + 2, nx2); vstep(t + 3, nx3); }
    vstep(t, nx0); vstep(t + 1, nx1); vstep(t + 2, nx2);  // t = 2045..2047

    v0 += ev.x; v1 += ev.y;
    float bv = v0; int bix = 2 * lane;
    if (v1 > bv) { bv = v1; bix = 2 * lane + 1; }
#pragma unroll
    for (int s = 1; s < 64; s <<= 1) {
      float ovv = __shfl_xor(bv, s, 64);
      int oi = __shfl_xor(bix, s, 64);
      if (ovv > bv || (ovv == bv && oi < bix)) { bv = ovv; bix = oi; }
    }
    if (lane == 0) best_last[b] = bix;
  }
}

__global__ __launch_bounds__(256) void gold_kernel(
    const float* __restrict__ em, const int* __restrict__ tags,
    const float* __restrict__ trans, const float* __restrict__ startv,
    const float* __restrict__ endv, float* __restrict__ gold) {
  __shared__ float red[256];
  int b = blockIdx.x, tid = threadIdx.x;
  const float* emb = em + (size_t)b * NT * NC;
  const int* tgb = tags + (size_t)b * NT;
  float acc = 0.f;
  for (int j = 0; j < NT / 256; ++j) {
    int t = tid + j * 256;
    int tg = tgb[t];
    acc += emb[(size_t)t * NC + tg];
    if (t < NT - 1) acc += trans[(size_t)tg * NC + tgb[t + 1]];
  }
  red[tid] = acc;
  __syncthreads();
  for (int s = 128; s > 0; s >>= 1) { if (tid < s) red[tid] += red[tid + s]; __syncthreads(); }
  if (tid == 0) gold[b] = red[0] + startv[tgb[0]] + endv[tgb[NT - 1]];
}

// Per (b,chunk): compose backpointers over the chunk -> 128->128 map.
__global__ __launch_bounds__(128) void maps_kernel(const float* __restrict__ out,
                                                   uint8_t* __restrict__ mmap) {
  __shared__ uint8_t bp[256 * 128];
  int bid = blockIdx.x, b = bid >> 3, c = bid & 7, tid = threadIdx.x;
  const char* ob = (const char*)out;
  int lo_t = c * 256 + 1;
  int nrows = (c == 7) ? 255 : 256;
  int nd = nrows * 32;
  for (int k = 0; k < 64; ++k) {
    int d = tid + k * 128;
    if (d < nd) {
      int row = d >> 5, col = d & 31;
      *(uint32_t*)&bp[(size_t)d * 4] =
          *(const uint32_t*)(ob + slot_off(b, lo_t + row) + (size_t)col * 4);
    }
  }
  __syncthreads();
  int cur = tid;
  for (int i = nrows - 1; i >= 0; --i) cur = bp[i * 128 + cur];
  mmap[b * 1024 + c * 128 + tid] = (uint8_t)cur;
}

// Combine maps: boundary states per chunk; also nll = sum(fpart) - gold.
__global__ void boundary_kernel(const uint8_t* __restrict__ mmap,
                                const int* __restrict__ best_last,
                                const float* __restrict__ fpart,
                                const float* __restrict__ gold,
                                uint8_t* __restrict__ TOPa,
                                float* __restrict__ out) {
  int b = threadIdx.x;
  const uint8_t* ob = (const uint8_t*)out;
  int e = best_last[b];                       // = path[2047]
  for (int c = 7; c >= 0; --c) {
    TOPa[b * 8 + c] = (c == 7) ? (uint8_t)e : ob[slot_off(b, 256 * (c + 1)) + e];
    e = mmap[b * 1024 + c * 128 + e];         // e = path[256c]
  }
  float z = 0.f;
  for (int c = 0; c < KF; ++c) z += fpart[b * KF + c];
  out[b] = z - gold[b];
}

// Replay each chunk from its known top state, emit one-hot rows (overwrites bp region).
__global__ __launch_bounds__(128) void replay_kernel(float* __restrict__ out,
                                                     const uint8_t* __restrict__ TOPa) {
  __shared__ uint8_t bp[255 * 128];
  __shared__ uint8_t path[256];
  int bid = blockIdx.x, b = bid >> 3, c = bid & 7, tid = threadIdx.x;
  char* ob = (char*)out;
  int lo_t = c * 256 + 1;
  const int nd = 255 * 32;
  for (int k = 0; k < 64; ++k) {
    int d = tid + k * 128;
    if (d < nd) {
      int row = d >> 5, col = d & 31;
      *(uint32_t*)&bp[(size_t)d * 4] =
          *(const uint32_t*)(ob + slot_off(b, lo_t + row) + (size_t)col * 4);
    }
  }
  __syncthreads();
  if (tid == 0) {
    int cur = TOPa[b * 8 + c];
    path[255] = (uint8_t)cur;
    for (int i = 254; i >= 0; --i) { cur = bp[i * 128 + cur]; path[i] = (uint8_t)cur; }
  }
  __syncthreads();
  for (int k = 0; k < 64; ++k) {
    int idx = tid + k * 128;
    int row = idx >> 5, j = idx & 31;
    int p = path[row];
    int c0 = j * 4;
    float4 val;
    val.x = (c0 + 0 == p) ? 1.f : 0.f;
    val.y = (c0 + 1 == p) ? 1.f : 0.f;
    val.z = (c0 + 2 == p) ? 1.f : 0.f;
    val.w = (c0 + 3 == p) ? 1.f : 0.f;
    *(float4*)(ob + slot_off(b, c * 256 + row) + (size_t)j * 16) = val;
  }
}

extern "C" void kernel_launch(void* const* d_in, const int* in_sizes, int n_in,
                              void* d_out, int out_size, void* d_ws, size_t ws_size,
                              hipStream_t stream) {
  const float* em = (const float*)d_in[0];
  const int* tags = (const int*)d_in[1];
  const float* trans = (const float*)d_in[2];
  const float* startv = (const float*)d_in[3];
  const float* endv = (const float*)d_in[4];
  float* out = (float*)d_out;
  char* ws = (char*)d_ws;
  float* fpart = (float*)(ws + 0);         // 64*32 f32 (8KB)
  float* gold = (float*)(ws + 8192);       // 64 f32
  int* best_last = (int*)(ws + 8448);      // 64 i32
  uint8_t* TOPa = (uint8_t*)(ws + 8704);   // 64*8 u8
  uint8_t* mmap = (uint8_t*)(ws + 9216);   // 64*1024 u8

  scan_kernel<<<dim3(NB + 512), dim3(256), 0, stream>>>(em, trans, startv, endv, out,
                                                        fpart, best_last);
  gold_kernel<<<dim3(64), dim3(256), 0, stream>>>(em, tags, trans, startv, endv, gold);
  maps_kernel<<<dim3(512), dim3(128), 0, stream>>>(out, mmap);
  boundary_kernel<<<dim3(1), dim3(64), 0, stream>>>(mmap, best_last, fpart, gold, TOPa, out);
  replay_kernel<<<dim3(512), dim3(128), 0, stream>>>(out, TOPa);
}

// Round 4
// 1332.731 us; speedup vs baseline: 2.8865x; 2.8865x over previous
//
#include <hip/hip_runtime.h>
#include <stdint.h>

#define NB 64
#define NT 2048
#define NC 128
#define KF 32          // forward chunks per batch
#define LF 64          // forward chunk length
#define WF 16          // forward warmup steps

typedef _Float16 h2 __attribute__((ext_vector_type(2)));

__device__ __forceinline__ h2 bc2(uint32_t u) { return __builtin_bit_cast(h2, u); }

__device__ __forceinline__ float fdot2f(h2 a, h2 b, float c) {
#if __has_builtin(__builtin_amdgcn_fdot2)
  return __builtin_amdgcn_fdot2(a, b, c, false);
#else
  float d;
  asm("v_dot2_f32_f16 %0, %1, %2, %3"
      : "=v"(d)
      : "v"(__builtin_bit_cast(uint32_t, a)), "v"(__builtin_bit_cast(uint32_t, b)), "v"(c));
  return d;
#endif
}

#define DPP_FMAX_STAGE(vv, ctrl)                                               \
  {                                                                            \
    int t_ = __builtin_amdgcn_update_dpp(vv, vv, ctrl, 0xf, 0xf, false);       \
    vv = __builtin_bit_cast(int, fmaxf(__builtin_bit_cast(float, vv),          \
                                       __builtin_bit_cast(float, t_)));        \
  }

__device__ __forceinline__ float wave_max_bcast(float x) {
  int v = __builtin_bit_cast(int, x);
  DPP_FMAX_STAGE(v, 0x111);
  DPP_FMAX_STAGE(v, 0x112);
  DPP_FMAX_STAGE(v, 0x114);
  DPP_FMAX_STAGE(v, 0x118);
  DPP_FMAX_STAGE(v, 0x142);
  DPP_FMAX_STAGE(v, 0x143);
  return __builtin_bit_cast(float, __builtin_amdgcn_readlane(v, 63));
}

// Byte offset of one-hot row (b,t) inside d_out (floats: 64 nll + (b*T+t)*128).
// First 128 bytes of each 512B row slot temporarily hold uint8 backpointers.
__device__ __forceinline__ size_t slot_off(int b, int t) {
  return ((size_t)64 + ((size_t)b * NT + t) * NC) * 4;
}

union ScanSM {
  float tr[NC * NC];          // viterbi: fp32 transitions (64KB)
  uint32_t ea[4][2][64];      // forward: [wave][dbuf][lane] exp(alpha) fp16x2
};

// grid: blocks [0,64) = viterbi (wave 0 only); [64, 64+512) = forward, 4
// independent chunk-waves per block (no intra-block sync -> share 64KB alloc).
__global__ __launch_bounds__(256, 1) void scan_kernel(
    const float* __restrict__ em, const float* __restrict__ trans,
    const float* __restrict__ startv, const float* __restrict__ endv,
    float* __restrict__ out, float* __restrict__ fpart, int* __restrict__ best_last) {
  __shared__ __align__(16) ScanSM sm;
  const int lane = threadIdx.x & 63;
  const int wid = threadIdx.x >> 6;

  if (blockIdx.x >= NB) {
    // ================= forward chunks (log partition pieces) =================
    const int fi = (blockIdx.x - NB) * 4 + wid;   // chunk id 0..2047
    const int b = fi >> 5, c = fi & 31;
    const int t0 = (c == 0) ? 0 : c * LF - WF;
    const int tend = (c == KF - 1) ? (NT - 1) : (c + 1) * LF;
    const float* emb = em + (size_t)b * NT * NC;

    h2 e0[64], e1[64];
#pragma unroll
    for (int j = 0; j < 64; ++j) {
      float2 r0 = *(const float2*)(trans + (size_t)(2 * j) * NC + 2 * lane);
      float2 r1 = *(const float2*)(trans + (size_t)(2 * j + 1) * NC + 2 * lane);
      h2 a, bb;
      a.x = (_Float16)__expf(r0.x);  a.y = (_Float16)__expf(r1.x);
      bb.x = (_Float16)__expf(r0.y); bb.y = (_Float16)__expf(r1.y);
      e0[j] = a; e1[j] = bb;
    }
    float2 ev = *(const float2*)(endv + 2 * lane);
    float2 em0 = *(const float2*)(emb + (size_t)t0 * NC + 2 * lane);
    float2 nx0 = *(const float2*)(emb + (size_t)(t0 + 1) * NC + 2 * lane);
    float2 nx1 = *(const float2*)(emb + (size_t)(t0 + 2) * NC + 2 * lane);
    float2 nx2 = *(const float2*)(emb + (size_t)(t0 + 3) * NC + 2 * lane);
    float2 nx3 = *(const float2*)(emb + (size_t)(t0 + 4) * NC + 2 * lane);
    float u0 = em0.x, u1 = em0.y;
    if (c == 0) {
      float2 sv = *(const float2*)(startv + 2 * lane);
      u0 += sv.x; u1 += sv.y;
    }
    float mu = 0.f;
    uint32_t* eab0 = &sm.ea[wid][0][0];
    uint32_t* eab1 = &sm.ea[wid][1][0];

    auto fstep = [&](int t, float2& nx) {
      h2 eh; eh.x = (_Float16)__expf(u0); eh.y = (_Float16)__expf(u1);
      uint32_t* eab = (t & 1) ? eab1 : eab0;
      eab[lane] = __builtin_bit_cast(uint32_t, eh);
      float nm = wave_max_bcast(fmaxf(u0, u1));  // overlaps LDS round-trip
      asm volatile("s_waitcnt lgkmcnt(0)" ::: "memory");
      float A0 = 0.f, A1 = 0.f, A2 = 0.f, A3 = 0.f;
#pragma unroll
      for (int q = 0; q < 16; ++q) {
        uint4 w = *(const uint4*)&eab[q * 4];
        A0 = fdot2f(bc2(w.x), e0[4 * q + 0], A0); A1 = fdot2f(bc2(w.x), e1[4 * q + 0], A1);
        A2 = fdot2f(bc2(w.y), e0[4 * q + 1], A2); A3 = fdot2f(bc2(w.y), e1[4 * q + 1], A3);
        A0 = fdot2f(bc2(w.z), e0[4 * q + 2], A0); A1 = fdot2f(bc2(w.z), e1[4 * q + 2], A1);
        A2 = fdot2f(bc2(w.w), e0[4 * q + 3], A2); A3 = fdot2f(bc2(w.w), e1[4 * q + 3], A3);
      }
      float o0 = nx.x - nm, o1 = nx.y - nm;
      u0 = __logf(A0 + A2) + o0;
      u1 = __logf(A1 + A3) + o1;
      mu += nm;
      if (t + 4 <= tend) nx = *(const float2*)(emb + (size_t)(t + 4) * NC + 2 * lane);
    };

    auto wave_lse = [&](float x0, float x1) -> float {
      float m = wave_max_bcast(fmaxf(x0, x1));
      float ss = __expf(x0 - m) + __expf(x1 - m);
#pragma unroll
      for (int s = 1; s < 64; s <<= 1) ss += __shfl_xor(ss, s, 64);
      return m + __logf(ss);
    };

    int t = t0 + 1;
    float m_start = 0.f;
    if (c > 0) {
      for (int j = 0; j < WF / 4; ++j) {
        fstep(t, nx0); fstep(t + 1, nx1); fstep(t + 2, nx2); fstep(t + 3, nx3);
        t += 4;
      }
      m_start = mu + wave_lse(u0, u1);
    }
    for (; t + 3 <= tend; t += 4) {
      fstep(t, nx0); fstep(t + 1, nx1); fstep(t + 2, nx2); fstep(t + 3, nx3);
    }
    int rem = tend - t + 1;  // 0..3
    if (rem > 0) fstep(t, nx0);
    if (rem > 1) fstep(t + 1, nx1);
    if (rem > 2) fstep(t + 2, nx2);

    float m_end;
    if (c == KF - 1) m_end = mu + wave_lse(u0 + ev.x, u1 + ev.y);
    else             m_end = mu + wave_lse(u0, u1);
    if (lane == 0) fpart[b * KF + c] = m_end - m_start;
  } else {
    // ================= viterbi (exact fp32, pruned max-plus) ==================
    // r2-proven loop mechanics; only the pruning bounds are per-lane (tighter).
    if (wid != 0) return;
    const int b = blockIdx.x;
    const float* emb = em + (size_t)b * NT * NC;
    char* ob = (char*)out;
    float* smv = sm.tr;
#pragma unroll 8
    for (int r = 0; r < NC; ++r) {
      *(float2*)&smv[r * NC + 2 * lane] =
          *(const float2*)(trans + (size_t)r * NC + 2 * lane);
    }
    // per-row max/min for exact pruning: rmx0/rmn0 for row 2*lane, rmx1/rmn1 row 2*lane+1
    float rmx0 = -INFINITY, rmn0 = INFINITY, rmx1 = -INFINITY, rmn1 = INFINITY;
    {
      const float* r0 = &smv[(2 * lane) * NC];
      const float* r1 = &smv[(2 * lane + 1) * NC];
      for (int j = 0; j < 32; ++j) {
        int k = ((lane + j) & 31) * 4;
        float4 a = *(const float4*)(r0 + k);
        float4 bq = *(const float4*)(r1 + k);
        rmx0 = fmaxf(rmx0, fmaxf(fmaxf(a.x, a.y), fmaxf(a.z, a.w)));
        rmn0 = fminf(rmn0, fminf(fminf(a.x, a.y), fminf(a.z, a.w)));
        rmx1 = fmaxf(rmx1, fmaxf(fmaxf(bq.x, bq.y), fmaxf(bq.z, bq.w)));
        rmn1 = fminf(rmn1, fminf(fminf(bq.x, bq.y), fminf(bq.z, bq.w)));
      }
    }

    float2 sv = *(const float2*)(startv + 2 * lane);
    float2 ev = *(const float2*)(endv + 2 * lane);
    float2 em0 = *(const float2*)(emb + 2 * lane);
    float2 nx0 = *(const float2*)(emb + (size_t)1 * NC + 2 * lane);
    float2 nx1 = *(const float2*)(emb + (size_t)2 * NC + 2 * lane);
    float2 nx2 = *(const float2*)(emb + (size_t)3 * NC + 2 * lane);
    float2 nx3 = *(const float2*)(emb + (size_t)4 * NC + 2 * lane);
    float v0 = sv.x + em0.x, v1 = sv.y + em0.y;  // v[2*lane], v[2*lane+1]

    auto vstep = [&](int t, float2& nx) {
      // thr = max_cf fl(v[cf]+rowmin[cf]) <= winner(ct) for every ct (fp-monotone)
      float thr = wave_max_bcast(fmaxf(v0 + rmn0, v1 + rmn1));
      unsigned long long m0 = __ballot(v0 + rmx0 >= thr);   // even cf = 2*l
      unsigned long long m1 = __ballot(v1 + rmx1 >= thr);   // odd  cf = 2*l+1
      float best0 = -INFINITY, best1 = -INFINITY;
      int bi0 = 0, bi1 = 0;

      auto proc = [&](int lc, float2 te, float2 to) {
        float vce = __builtin_bit_cast(float, __builtin_amdgcn_readlane(__builtin_bit_cast(int, v0), lc));
        float vco = __builtin_bit_cast(float, __builtin_amdgcn_readlane(__builtin_bit_cast(int, v1), lc));
        // ascending cf + strict '>' == first-index argmax; duplicates idempotent
        if ((m0 >> lc) & 1ull) {
          float s0 = vce + te.x, s1 = vce + te.y;
          bool g0 = s0 > best0; best0 = g0 ? s0 : best0; bi0 = g0 ? 2 * lc : bi0;
          bool g1 = s1 > best1; best1 = g1 ? s1 : best1; bi1 = g1 ? 2 * lc : bi1;
        }
        if ((m1 >> lc) & 1ull) {
          float s0 = vco + to.x, s1 = vco + to.y;
          bool g0 = s0 > best0; best0 = g0 ? s0 : best0; bi0 = g0 ? 2 * lc + 1 : bi0;
          bool g1 = s1 > best1; best1 = g1 ? s1 : best1; bi1 = g1 ? 2 * lc + 1 : bi1;
        }
      };

      unsigned long long rem = m0 | m1;   // never empty (thr-achieving lane qualifies)
      do {
        int l0 = (int)__builtin_ctzll(rem); rem &= rem - 1;
        int l1 = l0, l2 = l0, l3 = l0;
        if (rem) {
          l1 = (int)__builtin_ctzll(rem); rem &= rem - 1;
          if (rem) {
            l2 = (int)__builtin_ctzll(rem); rem &= rem - 1;
            if (rem) { l3 = (int)__builtin_ctzll(rem); rem &= rem - 1; }
          }
        }
        // batch-issue all 8 LDS reads for the group -> one latency wait
        const float2 teA = *(const float2*)&smv[(2 * l0) * NC + 2 * lane];
        const float2 toA = *(const float2*)&smv[(2 * l0) * NC + NC + 2 * lane];
        const float2 teB = *(const float2*)&smv[(2 * l1) * NC + 2 * lane];
        const float2 toB = *(const float2*)&smv[(2 * l1) * NC + NC + 2 * lane];
        const float2 teC = *(const float2*)&smv[(2 * l2) * NC + 2 * lane];
        const float2 toC = *(const float2*)&smv[(2 * l2) * NC + NC + 2 * lane];
        const float2 teD = *(const float2*)&smv[(2 * l3) * NC + 2 * lane];
        const float2 toD = *(const float2*)&smv[(2 * l3) * NC + NC + 2 * lane];
        proc(l0, teA, toA);
        proc(l1, teB, toB);
        proc(l2, teC, toC);
        proc(l3, teD, toD);
      } while (rem);

      v0 = best0 + nx.x; v1 = best1 + nx.y;
      if (t + 4 < NT) nx = *(const float2*)(emb + (size_t)(t + 4) * NC + 2 * lane);
      uint16_t pkd = (uint16_t)((bi0 & 0xff) | (bi1 << 8));
      *(uint16_t*)(ob + slot_off(b, t) + 2 * lane) = pkd;  // bp bytes into d_out slot
    };
    int t = 1;
    for (; t + 3 < NT; t += 4) { vstep(t, nx0); vstep(t + 1, nx1); vstep(t + 2, nx2); vstep(t + 3, nx3); }
    vstep(t, nx0); vstep(t + 1, nx1); vstep(t + 2, nx2);  // t = 2045..2047

    v0 += ev.x; v1 += ev.y;
    float bv = v0; int bix = 2 * lane;
    if (v1 > bv) { bv = v1; bix = 2 * lane + 1; }
#pragma unroll
    for (int s = 1; s < 64; s <<= 1) {
      float ovv = __shfl_xor(bv, s, 64);
      int oi = __shfl_xor(bix, s, 64);
      if (ovv > bv || (ovv == bv && oi < bix)) { bv = ovv; bix = oi; }
    }
    if (lane == 0) best_last[b] = bix;
  }
}

__global__ __launch_bounds__(256) void gold_kernel(
    const float* __restrict__ em, const int* __restrict__ tags,
    const float* __restrict__ trans, const float* __restrict__ startv,
    const float* __restrict__ endv, float* __restrict__ gold) {
  __shared__ float red[256];
  int b = blockIdx.x, tid = threadIdx.x;
  const float* emb = em + (size_t)b * NT * NC;
  const int* tgb = tags + (size_t)b * NT;
  float acc = 0.f;
  for (int j = 0; j < NT / 256; ++j) {
    int t = tid + j * 256;
    int tg = tgb[t];
    acc += emb[(size_t)t * NC + tg];
    if (t < NT - 1) acc += trans[(size_t)tg * NC + tgb[t + 1]];
  }
  red[tid] = acc;
  __syncthreads();
  for (int s = 128; s > 0; s >>= 1) { if (tid < s) red[tid] += red[tid + s]; __syncthreads(); }
  if (tid == 0) gold[b] = red[0] + startv[tgb[0]] + endv[tgb[NT - 1]];
}

// Per (b,chunk): compose backpointers over the chunk -> 128->128 map.
__global__ __launch_bounds__(128) void maps_kernel(const float* __restrict__ out,
                                                   uint8_t* __restrict__ mmap) {
  __shared__ uint8_t bp[256 * 128];
  int bid = blockIdx.x, b = bid >> 3, c = bid & 7, tid = threadIdx.x;
  const char* ob = (const char*)out;
  int lo_t = c * 256 + 1;
  int nrows = (c == 7) ? 255 : 256;
  int nd = nrows * 32;
  for (int k = 0; k < 64; ++k) {
    int d = tid + k * 128;
    if (d < nd) {
      int row = d >> 5, col = d & 31;
      *(uint32_t*)&bp[(size_t)d * 4] =
          *(const uint32_t*)(ob + slot_off(b, lo_t + row) + (size_t)col * 4);
    }
  }
  __syncthreads();
  int cur = tid;
  for (int i = nrows - 1; i >= 0; --i) cur = bp[i * 128 + cur];
  mmap[b * 1024 + c * 128 + tid] = (uint8_t)cur;
}

// Combine maps: boundary states per chunk; also nll = sum(fpart) - gold.
__global__ void boundary_kernel(const uint8_t* __restrict__ mmap,
                                const int* __restrict__ best_last,
                                const float* __restrict__ fpart,
                                const float* __restrict__ gold,
                                uint8_t* __restrict__ TOPa,
                                float* __restrict__ out) {
  int b = threadIdx.x;
  const uint8_t* ob = (const uint8_t*)out;
  int e = best_last[b];                       // = path[2047]
  for (int c = 7; c >= 0; --c) {
    TOPa[b * 8 + c] = (c == 7) ? (uint8_t)e : ob[slot_off(b, 256 * (c + 1)) + e];
    e = mmap[b * 1024 + c * 128 + e];         // e = path[256c]
  }
  float z = 0.f;
  for (int c = 0; c < KF; ++c) z += fpart[b * KF + c];
  out[b] = z - gold[b];
}

// Replay each chunk from its known top state, emit one-hot rows (overwrites bp region).
__global__ __launch_bounds__(128) void replay_kernel(float* __restrict__ out,
                                                     const uint8_t* __restrict__ TOPa) {
  __shared__ uint8_t bp[255 * 128];
  __shared__ uint8_t path[256];
  int bid = blockIdx.x, b = bid >> 3, c = bid & 7, tid = threadIdx.x;
  char* ob = (char*)out;
  int lo_t = c * 256 + 1;
  const int nd = 255 * 32;
  for (int k = 0; k < 64; ++k) {
    int d = tid + k * 128;
    if (d < nd) {
      int row = d >> 5, col = d & 31;
      *(uint32_t*)&bp[(size_t)d * 4] =
          *(const uint32_t*)(ob + slot_off(b, lo_t + row) + (size_t)col * 4);
    }
  }
  __syncthreads();
  if (tid == 0) {
    int cur = TOPa[b * 8 + c];
    path[255] = (uint8_t)cur;
    for (int i = 254; i >= 0; --i) { cur = bp[i * 128 + cur]; path[i] = (uint8_t)cur; }
  }
  __syncthreads();
  for (int k = 0; k < 64; ++k) {
    int idx = tid + k * 128;
    int row = idx >> 5, j = idx & 31;
    int p = path[row];
    int c0 = j * 4;
    float4 val;
    val.x = (c0 + 0 == p) ? 1.f : 0.f;
    val.y = (c0 + 1 == p) ? 1.f : 0.f;
    val.z = (c0 + 2 == p) ? 1.f : 0.f;
    val.w = (c0 + 3 == p) ? 1.f : 0.f;
    *(float4*)(ob + slot_off(b, c * 256 + row) + (size_t)j * 16) = val;
  }
}

extern "C" void kernel_launch(void* const* d_in, const int* in_sizes, int n_in,
                              void* d_out, int out_size, void* d_ws, size_t ws_size,
                              hipStream_t stream) {
  const float* em = (const float*)d_in[0];
  const int* tags = (const int*)d_in[1];
  const float* trans = (const float*)d_in[2];
  const float* startv = (const float*)d_in[3];
  const float* endv = (const float*)d_in[4];
  float* out = (float*)d_out;
  char* ws = (char*)d_ws;
  float* fpart = (float*)(ws + 0);         // 64*32 f32 (8KB)
  float* gold = (float*)(ws + 8192);       // 64 f32
  int* best_last = (int*)(ws + 8448);      // 64 i32
  uint8_t* TOPa = (uint8_t*)(ws + 8704);   // 64*8 u8
  uint8_t* mmap = (uint8_t*)(ws + 9216);   // 64*1024 u8

  scan_kernel<<<dim3(NB + 512), dim3(256), 0, stream>>>(em, trans, startv, endv, out,
                                                        fpart, best_last);
  gold_kernel<<<dim3(64), dim3(256), 0, stream>>>(em, tags, trans, startv, endv, gold);
  maps_kernel<<<dim3(512), dim3(128), 0, stream>>>(out, mmap);
  boundary_kernel<<<dim3(1), dim3(64), 0, stream>>>(mmap, best_last, fpart, gold, TOPa, out);
  replay_kernel<<<dim3(512), dim3(128), 0, stream>>>(out, TOPa);
}